// Round 2
// baseline (309.063 us; speedup 1.0000x reference)
//
#include <hip/hip_runtime.h>

#define NEGV  (-1.0e30f)
#define EPSF  (1e-7f)
#define LN2F  (0.6931471805599453f)

#if __has_builtin(__builtin_amdgcn_exp2f)
#define EXP2(x) __builtin_amdgcn_exp2f(x)
#else
#define EXP2(x) exp2f(x)
#endif
#if __has_builtin(__builtin_amdgcn_logf)
#define LOG2(x) __builtin_amdgcn_logf(x)
#else
#define LOG2(x) __log2f(x)
#endif

// Full-wave shift-up-by-1 in registers: DPP row_shr:1 within 16-lane rows,
// row_bcast15 supplies lanes 16/32/48 from lanes 15/31/47. Lane 0 result is
// garbage (0) — callers must select it away (they do, via a0 / skip).
__device__ __forceinline__ float shift_up1(float x, bool rowhead) {
    int xi = __float_as_int(x);
    int sh = __builtin_amdgcn_update_dpp(xi, xi, 0x111, 0xF, 0xF, true); // row_shr:1
    int bc = __builtin_amdgcn_update_dpp(xi, xi, 0x142, 0xF, 0xF, true); // row_bcast15
    return __int_as_float(rowhead ? bc : sh);
}

// One wave per batch element. Lane i owns states s=2i+1 (label labels[i])
// and s=2i+2 (blank). State s=0 is the scalar a0 (replicated on all lanes).
// Entire recursion in log2 domain (native v_exp_f32 / v_log_f32); scale by
// ln2 only at the end.
template<int D>
__global__ __launch_bounds__(64, 1)
void ctc_fwd_kernel(const float* __restrict__ y_pred,
                    const int*   __restrict__ labels,
                    const int*   __restrict__ input_length,
                    const int*   __restrict__ label_length,
                    float*       __restrict__ out,
                    int T, int C, int L)
{
    const int b    = blockIdx.x;
    const int lane = threadIdx.x;          // 0..63
    const int Tin  = input_length[b];
    const int ll   = label_length[b];

    const int  l     = labels[(size_t)b * L + lane];   // 0..C-2, never blank
    const int  lprev = __shfl_up(l, 1);                // one-time DS op, off-loop
    const bool skip  = (lane >= 1) && (l != lprev);
    const bool rowhead = ((lane & 15) == 0);

    const float* base = y_pred + (size_t)b * T * C;
    const float* plab = base + l;        // lane's label prob, + t*C per step
    const float* pblk = base + (C - 1);  // blank prob (uniform addr -> bcast)

    float vl[D], vb[D];
#pragma unroll
    for (int j = 0; j < D; ++j) {
        vl[j] = plab[(size_t)j * C];
        vb[j] = pblk[(size_t)j * C];
    }

    float a0 = NEGV, ao = NEGV, ae = NEGV;

    for (int tb = 0; tb < T; tb += D) {
#pragma unroll
        for (int j = 0; j < D; ++j) {
            float yl = vl[j], yb = vb[j];
            int tn = tb + j + D;
            if (tn < T) {                           // prefetch, D loads in flight
                vl[j] = plab[(size_t)tn * C];
                vb[j] = pblk[(size_t)tn * C];
            }
            int t = tb + j;
            if (t < Tin) {                          // wave-uniform
                float lpl = LOG2(yl + EPSF);        // off-chain
                float lpb = LOG2(yb + EPSF);
                if (t == 0) {
                    a0 = lpb;
                    ao = (lane == 0) ? lpl : NEGV;
                    ae = NEGV;
                } else {
                    float sae = shift_up1(ae, rowhead);   // alpha[2i]   (old)
                    float sao = shift_up1(ao, rowhead);   // alpha[2i-1] (old)
                    float a2  = (lane == 0) ? a0 : sae;
                    float a3  = skip ? sao : NEGV;
                    // odd state s=2i+1: lse3(ao, a2, a3) + lpl
                    float m1  = fmaxf(fmaxf(ao, a2), a3);
                    float s1  = EXP2(ao - m1) + EXP2(a2 - m1) + EXP2(a3 - m1);
                    float nao = m1 + LOG2(s1) + lpl;
                    // even state s=2i+2 (blank, no skip): lse2(ae, ao) + lpb
                    float m2  = fmaxf(ae, ao);
                    float s2  = EXP2(ae - m2) + EXP2(ao - m2);
                    float nae = m2 + LOG2(s2) + lpb;
                    a0 += lpb;                      // s=0: self-transition only
                    ao = nao;
                    ae = nae;
                }
            }
        }
    }

    // s_end = 2*ll -> lane (ll-1).ae ; s_end-1 -> lane (ll-1).ao ; ll >= 16
    if (lane == ll - 1) {
        float m = fmaxf(ae, ao);
        float r = m + LOG2(EXP2(ae - m) + EXP2(ao - m));
        out[b] = -r * LN2F;
    }
}

extern "C" void kernel_launch(void* const* d_in, const int* in_sizes, int n_in,
                              void* d_out, int out_size, void* d_ws, size_t ws_size,
                              hipStream_t stream) {
    const float* y_pred       = (const float*)d_in[0];
    const int*   labels       = (const int*)d_in[1];
    const int*   input_length = (const int*)d_in[2];
    const int*   label_length = (const int*)d_in[3];
    float*       out          = (float*)d_out;

    const int B = in_sizes[2];          // 256
    const int L = in_sizes[1] / B;      // 64
    const int T = 512;
    const int C = 128;

    ctc_fwd_kernel<16><<<B, 64, 0, stream>>>(y_pred, labels, input_length,
                                             label_length, out, T, C, L);
}

// Round 3
// 141.652 us; speedup vs baseline: 2.1818x; 2.1818x over previous
//
#include <hip/hip_runtime.h>

#define NEGV  (-1.0e30f)
#define EPSF  (1e-7f)
#define LN2F  (0.69314718055994530942f)

#if __has_builtin(__builtin_amdgcn_exp2f)
#define EXP2(x) __builtin_amdgcn_exp2f(x)
#else
#define EXP2(x) exp2f(x)
#endif
#if __has_builtin(__builtin_amdgcn_logf)
#define LOG2(x) __builtin_amdgcn_logf(x)
#else
#define LOG2(x) __log2f(x)
#endif

// Full-wave shift-up-by-1 in registers (no DS): row_shr:1 within 16-lane rows,
// row_bcast15 fills lanes 16/32/48 from lanes 15/31/47. Lane 0 is garbage —
// always selected away by caller (a0 / skip).
__device__ __forceinline__ float shift_up1(float x, bool rowhead) {
    int xi = __float_as_int(x);
    int sh = __builtin_amdgcn_update_dpp(xi, xi, 0x111, 0xF, 0xF, true); // row_shr:1
    int bc = __builtin_amdgcn_update_dpp(xi, xi, 0x142, 0xF, 0xF, true); // row_bcast15
    return __int_as_float(rowhead ? bc : sh);
}

// One wave per batch element. Lane i owns states s=2i+1 (label labels[i]) and
// s=2i+2 (blank); s=0 is the scalar a0. Whole recursion in log2 domain,
// scaled by ln2 at the end. Two-phase pipeline: batched gathers (bpermute,
// off-chain) feed 16-step chain blocks (DPP + exp2/log2 only).
__global__ __launch_bounds__(64, 1)
void ctc_fwd_kernel(const float* __restrict__ y_pred,
                    const int*   __restrict__ labels,
                    const int*   __restrict__ input_length,
                    const int*   __restrict__ label_length,
                    float*       __restrict__ out,
                    int T, int C, int L)
{
    const int b    = blockIdx.x;
    const int lane = threadIdx.x;              // 0..63
    const int Tin  = input_length[b];
    const int ll   = label_length[b];

    const int  l       = labels[(size_t)b * L + lane];   // 0..C-2, never blank
    const int  lprev   = __shfl_up(l, 1);                // one-time DS op
    const bool skip    = (lane >= 1) && (l != lprev);
    const bool rowhead = ((lane & 15) == 0);
    const bool lane0   = (lane == 0);
    const int  src     = l >> 1;                         // lane holding class l
    const bool comp    = (l & 1) != 0;

    const float2* rowp = (const float2*)(y_pred + (size_t)b * T * C) + lane;
    const int rstride  = C >> 1;               // 64 float2 per row

    float2 buf[16];
    float ylA[16], ybA[16], lbA[16];           // y_label+eps, y_blank+eps, log2(y_blank+eps)
    float ylB[16], ybB[16], lbB[16];
    float a0 = NEGV, ao = NEGV, ae = NEGV;

    auto prefetch = [&](int t0) {
        #pragma unroll
        for (int j = 0; j < 16; ++j) {
            int t = t0 + j; t = (t < T) ? t : (T - 1);   // clamp: harmless dup loads
            buf[j] = rowp[(size_t)t * rstride];
        }
    };
    auto gather = [&](float* yl, float* yb, float* lb) {
        #pragma unroll
        for (int j = 0; j < 16; ++j) {
            float2 y = buf[j];
            float gx = __shfl(y.x, src);                 // ds_bpermute (batched)
            float gy = __shfl(y.y, src);
            float gb = __int_as_float(
                __builtin_amdgcn_readlane(__float_as_int(y.y), 63)); // blank, SGPR
            yl[j] = (comp ? gy : gx) + EPSF;
            yb[j] = gb + EPSF;
            lb[j] = LOG2(gb + EPSF);
        }
    };
    auto chain = [&](const float* yl, const float* yb, const float* lb, int t0) {
        #pragma unroll
        for (int j = 0; j < 16; ++j) {
            int t = t0 + j;
            if (t < Tin) {                               // wave-uniform
                if (t == 0) {
                    a0 = lb[0];
                    ao = lane0 ? LOG2(yl[0]) : NEGV;
                    ae = NEGV;
                } else {
                    float sae = shift_up1(ae, rowhead);  // alpha[2i]   (old)
                    float sao = shift_up1(ao, rowhead);  // alpha[2i-1] (old)
                    float a2  = lane0 ? a0 : sae;
                    float a3  = skip ? sao : NEGV;
                    // s=2i+1: lse3(ao,a2,a3) + log2(y_lab+eps)  (log folded via mul)
                    float hi  = fmaxf(fmaxf(ao, a2), a3);
                    float s1  = EXP2(ao - hi) + EXP2(a2 - hi) + EXP2(a3 - hi);
                    float nao = hi + LOG2(s1 * yl[j]);
                    // s=2i+2 (blank, no skip): lse2(ae,ao) + log2(y_blank+eps)
                    float m2  = fmaxf(ae, ao);
                    float s2  = EXP2(ae - m2) + EXP2(ao - m2);
                    float nae = m2 + LOG2(s2 * yb[j]);
                    a0 += lb[j];                         // s=0: self-transition only
                    ao = nao;
                    ae = nae;
                }
            }
        }
    };

    const int NB = T / 16;                               // 32, even
    prefetch(0);
    gather(ylA, ybA, lbA);                               // block 0
    prefetch(16);
    for (int kb = 0; kb < NB; kb += 2) {
        if (kb + 1 < NB) gather(ylB, ybB, lbB);          // block kb+1 (off-chain)
        prefetch((kb + 2) * 16);
        chain(ylA, ybA, lbA, kb * 16);
        if (kb + 2 < NB) gather(ylA, ybA, lbA);          // block kb+2 (off-chain)
        prefetch((kb + 3) * 16);
        if (kb + 1 < NB) chain(ylB, ybB, lbB, (kb + 1) * 16);
    }

    // s_end = 2*ll -> lane (ll-1).ae ; s_end-1 -> lane (ll-1).ao ; ll >= 16
    if (lane == ll - 1) {
        float m = fmaxf(ae, ao);
        float r = m + LOG2(EXP2(ae - m) + EXP2(ao - m));
        out[b] = -r * LN2F;
    }
}

extern "C" void kernel_launch(void* const* d_in, const int* in_sizes, int n_in,
                              void* d_out, int out_size, void* d_ws, size_t ws_size,
                              hipStream_t stream) {
    const float* y_pred       = (const float*)d_in[0];
    const int*   labels       = (const int*)d_in[1];
    const int*   input_length = (const int*)d_in[2];
    const int*   label_length = (const int*)d_in[3];
    float*       out          = (float*)d_out;

    const int B = in_sizes[2];          // 256
    const int L = in_sizes[1] / B;      // 64
    const int T = 512;
    const int C = 128;

    ctc_fwd_kernel<<<B, 64, 0, stream>>>(y_pred, labels, input_length,
                                         label_length, out, T, C, L);
}

// Round 6
// 129.084 us; speedup vs baseline: 2.3943x; 1.0974x over previous
//
#include <hip/hip_runtime.h>

#define EPSF  (1e-7f)
#define LN2F  (0.69314718055994530942f)

#if __has_builtin(__builtin_amdgcn_logf)
#define LOG2(x) __builtin_amdgcn_logf(x)
#else
#define LOG2(x) __log2f(x)
#endif

// DPP move; ctrl is a template constant. bound_ctrl=1 -> invalid lanes read 0.
template<int CTRL>
__device__ __forceinline__ int dpp_i(int x) {
    return __builtin_amdgcn_update_dpp(x, x, CTRL, 0xF, 0xF, true);
}

// Full-wave shift-up-by-1 in registers (no DS): row_shr:1 within 16-lane rows,
// row_bcast15 fills lanes 16/32/48 from 15/31/47 (bit-exact verified R2/R3).
// Lane 0 result is garbage — always selected away by callers.
__device__ __forceinline__ float shift_up1_f(float x, bool rowhead) {
    int xi = __float_as_int(x);
    int sh = dpp_i<0x111>(xi);
    int bc = dpp_i<0x142>(xi);
    return __int_as_float(rowhead ? bc : sh);
}
__device__ __forceinline__ int shift_up1_i(int x, bool rowhead) {
    int sh = dpp_i<0x111>(x);
    int bc = dpp_i<0x142>(x);
    return rowhead ? bc : sh;
}

// One wave per batch element. Lane i owns states s=2i+1 (label labels[i]) and
// s=2i+2 (blank); s=0 is a0 (tracked on every lane, used by lane 0).
// LINEAR-domain forward recursion — no exp/log on the chain. Every lane keeps
// its own scale: value_stored = value_true * 2^-esum_lane. Renorm every 4
// steps to the lane's own state max (a0-anchored while states are zero).
// Cross-lane shifts are rescaled by fsc = 2^(esum_prevlane - esum_lane),
// constant within each 4-step window.
__global__ __launch_bounds__(64, 1)
void ctc_fwd_kernel(const float* __restrict__ y_pred,
                    const int*   __restrict__ labels,
                    const int*   __restrict__ input_length,
                    const int*   __restrict__ label_length,
                    float*       __restrict__ out,
                    int T, int C, int L)
{
    const int b    = blockIdx.x;
    const int lane = threadIdx.x;              // 0..63
    const int Tin  = input_length[b];
    const int ll   = label_length[b];

    const int  l       = labels[(size_t)b * L + lane];   // 0..C-2, never blank
    const int  lprev   = __shfl_up(l, 1);                // one-time DS op
    const bool skip    = (lane >= 1) && (l != lprev);
    const bool rowhead = ((lane & 15) == 0);
    const bool lane0   = (lane == 0);
    const int  src     = l >> 1;                         // lane holding class l
    const bool comp    = (l & 1) != 0;

    const float2* rowp = (const float2*)(y_pred + (size_t)b * T * C) + lane;
    const int rstride  = C >> 1;               // 64 float2 per row

    float2 buf[16];
    float ylA[16], ybA[16];                    // y_label+eps, y_blank+eps
    float ylB[16], ybB[16];
    float a0 = 0.0f, ao = 0.0f, ae = 0.0f;
    int   esum = 0;                            // per-lane exponent tally
    float fsc  = 1.0f;                         // 2^(esum_prev - esum_self)

    auto prefetch = [&](int t0) {
        #pragma unroll
        for (int j = 0; j < 16; ++j) {
            int t = t0 + j; t = (t < T) ? t : (T - 1);   // clamp: harmless dups
            buf[j] = rowp[(size_t)t * rstride];
        }
    };
    auto gather = [&](float* yl, float* yb) {
        #pragma unroll
        for (int j = 0; j < 16; ++j) {
            float2 y = buf[j];
            float gx = __shfl(y.x, src);                 // ds_bpermute (batched)
            float gy = __shfl(y.y, src);
            float gb = __int_as_float(
                __builtin_amdgcn_readlane(__float_as_int(y.y), 63)); // blank
            yl[j] = (comp ? gy : gx) + EPSF;
            yb[j] = gb + EPSF;
        }
    };
    auto renorm = [&]() {
        float lm    = fmaxf(ae, ao);
        float basis = (lm > 0.0f) ? lm : a0;             // a0-anchor while dead
        int   e  = (__float_as_int(basis) >> 23) & 0xFF; // biased exponent
        float sc = __int_as_float((254 - e) << 23);      // 2^(127-e)
        ae *= sc; ao *= sc; a0 *= sc;
        esum += e - 127;
        int en = shift_up1_i(esum, rowhead);             // prev lane's new esum
        int de = en - esum;
        de = de < -127 ? -127 : (de > 127 ? 127 : de);
        fsc = __int_as_float((127 + de) << 23);          // 2^de (0 if de=-127)
    };
    auto chain = [&](const float* yl, const float* yb, int t0) {
        #pragma unroll
        for (int j = 0; j < 16; ++j) {
            int t = t0 + j;
            if (t < Tin) {                               // wave-uniform
                if (t == 0) {
                    a0 = yb[0];
                    ao = lane0 ? yl[0] : 0.0f;
                    ae = 0.0f;
                } else {
                    float sae = shift_up1_f(ae, rowhead);  // alpha[2i]   (old)
                    float sao = shift_up1_f(ao, rowhead);  // alpha[2i-1] (old)
                    float a2  = lane0 ? a0 : sae * fsc;
                    float a3  = skip ? sao * fsc : 0.0f;
                    float nao = (ao + a2 + a3) * yl[j];    // s=2i+1
                    float nae = (ae + ao) * yb[j];         // s=2i+2 (blank)
                    a0 *= yb[j];                           // s=0
                    ao = nao;
                    ae = nae;
                }
            }
            if ((j & 3) == 3) renorm();                  // every 4 steps
        }
    };

    const int NB = T / 16;                               // 32, even
    prefetch(0);
    gather(ylA, ybA);                                    // block 0
    prefetch(16);
    for (int kb = 0; kb < NB; kb += 2) {
        if (kb + 1 < NB) gather(ylB, ybB);               // block kb+1 (off-chain)
        prefetch((kb + 2) * 16);
        chain(ylA, ybA, kb * 16);
        if (kb + 2 < NB) gather(ylA, ybA);               // block kb+2 (off-chain)
        prefetch((kb + 3) * 16);
        if (kb + 1 < NB) chain(ylB, ybB, (kb + 1) * 16);
    }

    // s_end = 2*ll -> lane (ll-1).ae ; s_end-1 -> lane (ll-1).ao ; ll >= 16
    if (lane == ll - 1) {
        float p = ae + ao;                               // lane's own scale
        out[b] = -(LOG2(p) + (float)esum) * LN2F;
    }
}

extern "C" void kernel_launch(void* const* d_in, const int* in_sizes, int n_in,
                              void* d_out, int out_size, void* d_ws, size_t ws_size,
                              hipStream_t stream) {
    const float* y_pred       = (const float*)d_in[0];
    const int*   labels       = (const int*)d_in[1];
    const int*   input_length = (const int*)d_in[2];
    const int*   label_length = (const int*)d_in[3];
    float*       out          = (float*)d_out;

    const int B = in_sizes[2];          // 256
    const int L = in_sizes[1] / B;      // 64
    const int T = 512;
    const int C = 128;

    ctc_fwd_kernel<<<B, 64, 0, stream>>>(y_pred, labels, input_length,
                                         label_length, out, T, C, L);
}

// Round 7
// 124.856 us; speedup vs baseline: 2.4754x; 1.0339x over previous
//
#include <hip/hip_runtime.h>

#define EPSF  (1e-7f)
#define LN2F  (0.69314718055994530942f)

#if __has_builtin(__builtin_amdgcn_logf)
#define LOG2(x) __builtin_amdgcn_logf(x)
#else
#define LOG2(x) __log2f(x)
#endif

// DPP move; ctrl is a template constant. bound_ctrl=1 -> invalid lanes read 0.
template<int CTRL>
__device__ __forceinline__ int dpp_i(int x) {
    return __builtin_amdgcn_update_dpp(x, x, CTRL, 0xF, 0xF, true);
}

// Full-wave shift-up-by-1 in registers (no DS): row_shr:1 within 16-lane rows,
// row_bcast15 fills lanes 16/32/48 from 15/31/47 (bit-exact verified R2-R6).
// Lane 0 result is garbage — always selected away by callers.
__device__ __forceinline__ float shift_up1_f(float x, bool rowhead) {
    int xi = __float_as_int(x);
    int sh = dpp_i<0x111>(xi);
    int bc = dpp_i<0x142>(xi);
    return __int_as_float(rowhead ? bc : sh);
}
__device__ __forceinline__ int shift_up1_i(int x, bool rowhead) {
    int sh = dpp_i<0x111>(x);
    int bc = dpp_i<0x142>(x);
    return rowhead ? bc : sh;
}

// One wave per batch element. Lane i owns states s=2i+1 (label labels[i]) and
// s=2i+2 (blank); s=0 is a0. LINEAR-domain recursion with per-lane power-of-2
// scaling (renorm every 4 steps), proven exact in R6. Gathers run through LDS:
// coalesced global->VGPR->ds_write_b64 staging, then divergent ds_read_b32
// (issue-cost only, compiler-tracked deps) one phase ahead of the chain.
__global__ __launch_bounds__(64, 1)
void ctc_fwd_kernel(const float* __restrict__ y_pred,
                    const int*   __restrict__ labels,
                    const int*   __restrict__ input_length,
                    const int*   __restrict__ label_length,
                    float*       __restrict__ out,
                    int T, int C, int L)
{
    const int b    = blockIdx.x;
    const int lane = threadIdx.x;              // 0..63
    const int Tin  = input_length[b];
    const int ll   = label_length[b];

    const int  l       = labels[(size_t)b * L + lane];   // 0..C-2, never blank
    const int  lprev   = __shfl_up(l, 1);                // one-time DS op
    const bool skip    = (lane >= 1) && (l != lprev);
    const bool rowhead = ((lane & 15) == 0);
    const bool lane0   = (lane == 0);

    __shared__ float smem[2][16][128];         // 2 phase regions x 16 rows

    const float2* rowp = (const float2*)(y_pred + (size_t)b * T * C) + lane;

    float2 bufA[16], bufB[16];
    float ylA[16], ylB[16], ybA[16], ybB[16];
    float a0 = 0.0f, ao = 0.0f, ae = 0.0f;
    int   esum = 0;                            // per-lane exponent tally
    float fsc  = 1.0f;                         // 2^(esum_prev - esum_self)

    auto loadbuf = [&](float2* buf, int t0) {
        #pragma unroll
        for (int j = 0; j < 16; ++j) {
            int t = t0 + j; t = (t < T) ? t : (T - 1);   // clamp: harmless dups
            buf[j] = rowp[(size_t)t * 64];
        }
    };
    auto stage = [&](int r, const float2* buf, float* yb) {
        #pragma unroll
        for (int j = 0; j < 16; ++j) {
            yb[j] = __int_as_float(__builtin_amdgcn_readlane(
                        __float_as_int(buf[j].y), 63)) + EPSF;  // blank col 127
            *(float2*)&smem[r][j][2 * lane] = buf[j];           // ds_write_b64
        }
    };
    auto readyl = [&](int r, float* yl) {
        #pragma unroll
        for (int j = 0; j < 16; ++j)
            yl[j] = smem[r][j][l] + EPSF;                       // divergent ds_read
    };
    auto renorm = [&]() {
        float lm    = fmaxf(ae, ao);
        float basis = (lm > 0.0f) ? lm : a0;             // a0-anchor while dead
        int   e  = (__float_as_int(basis) >> 23) & 0xFF; // biased exponent
        float sc = __int_as_float((254 - e) << 23);      // 2^(127-e)
        ae *= sc; ao *= sc; a0 *= sc;
        esum += e - 127;
        int en = shift_up1_i(esum, rowhead);             // prev lane's new esum
        int de = en - esum;
        de = de < -127 ? -127 : (de > 127 ? 127 : de);
        fsc = __int_as_float((127 + de) << 23);          // 2^de
    };
    auto chain = [&](const float* yl, const float* yb, int t0) {
        #pragma unroll
        for (int j = 0; j < 16; ++j) {
            int t = t0 + j;
            if (t < Tin) {                               // wave-uniform
                if (t == 0) {
                    a0 = yb[0];
                    ao = lane0 ? yl[0] : 0.0f;
                    ae = 0.0f;
                } else {
                    float sae = shift_up1_f(ae, rowhead);  // alpha[2i]   (old)
                    float sao = shift_up1_f(ao, rowhead);  // alpha[2i-1] (old)
                    float a2  = lane0 ? a0 : sae * fsc;
                    float a3  = skip ? sao * fsc : 0.0f;
                    float nao = (ao + a2 + a3) * yl[j];    // s=2i+1
                    float nae = (ae + ao) * yb[j];         // s=2i+2 (blank)
                    a0 *= yb[j];                           // s=0
                    ao = nao;
                    ae = nae;
                }
            }
            if ((j & 3) == 3) renorm();                  // every 4 steps
        }
    };

    // Pipeline prologue: bufA=phase0, bufB=phase1, stage+gather phase0,
    // bufA reloads phase2.
    loadbuf(bufA, 0);
    loadbuf(bufB, 16);
    stage(0, bufA, ybA);
    loadbuf(bufA, 32);
    readyl(0, ylA);

    // Invariant at loop head: ylA/ybA = phase p (gathered); bufB = phase p+1
    // rows (in regs); bufA = phase p+2 rows (in flight).
    for (int p = 0; p < 32; p += 2) {
        stage(1, bufB, ybB);               // phase p+1 -> region 1
        loadbuf(bufB, (p + 3) * 16);       // phase p+3 (clamped at tail)
        readyl(1, ylB);                    // phase p+1 gathers (ahead of chain)
        chain(ylA, ybA, p * 16);

        stage(0, bufA, ybA);               // phase p+2 -> region 0
        loadbuf(bufA, (p + 4) * 16);       // phase p+4 (clamped at tail)
        readyl(0, ylA);                    // phase p+2 gathers
        chain(ylB, ybB, (p + 1) * 16);
    }

    // s_end = 2*ll -> lane (ll-1).ae ; s_end-1 -> lane (ll-1).ao ; ll >= 16
    if (lane == ll - 1) {
        float p = ae + ao;                               // lane's own scale
        out[b] = -(LOG2(p) + (float)esum) * LN2F;
    }
}

extern "C" void kernel_launch(void* const* d_in, const int* in_sizes, int n_in,
                              void* d_out, int out_size, void* d_ws, size_t ws_size,
                              hipStream_t stream) {
    const float* y_pred       = (const float*)d_in[0];
    const int*   labels       = (const int*)d_in[1];
    const int*   input_length = (const int*)d_in[2];
    const int*   label_length = (const int*)d_in[3];
    float*       out          = (float*)d_out;

    const int B = in_sizes[2];          // 256
    const int L = in_sizes[1] / B;      // 64
    const int T = 512;
    const int C = 128;

    ctc_fwd_kernel<<<B, 64, 0, stream>>>(y_pred, labels, input_length,
                                         label_length, out, T, C, L);
}

// Round 8
// 114.902 us; speedup vs baseline: 2.6898x; 1.0866x over previous
//
#include <hip/hip_runtime.h>

#define EPSF  (1e-7f)
#define LN2F  (0.69314718055994530942f)

#if __has_builtin(__builtin_amdgcn_logf)
#define LOG2(x) __builtin_amdgcn_logf(x)
#else
#define LOG2(x) __log2f(x)
#endif

// DPP move; ctrl is a template constant. bound_ctrl=1 -> invalid lanes read 0.
template<int CTRL>
__device__ __forceinline__ int dpp_i(int x) {
    return __builtin_amdgcn_update_dpp(x, x, CTRL, 0xF, 0xF, true);
}

// Full-wave shift-up-by-1 in registers (no DS): row_shr:1 within 16-lane rows,
// row_bcast15 fills lanes 16/32/48 from 15/31/47 (bit-exact verified R2-R7).
// Lane 0 result is garbage — always selected away by callers.
__device__ __forceinline__ float shift_up1_f(float x, bool rowhead) {
    int xi = __float_as_int(x);
    int sh = dpp_i<0x111>(xi);
    int bc = dpp_i<0x142>(xi);
    return __int_as_float(rowhead ? bc : sh);
}
__device__ __forceinline__ int shift_up1_i(int x, bool rowhead) {
    int sh = dpp_i<0x111>(x);
    int bc = dpp_i<0x142>(x);
    return rowhead ? bc : sh;
}

// Raw workgroup barrier WITHOUT the compiler's vmcnt(0) drain (that drain is
// the m97-style stall). Producer guarantees data residency with its own
// fine-grained s_waitcnt before signaling. asm clobbers stop compile-time
// motion of LDS/global accesses across the barrier.
__device__ __forceinline__ void wg_barrier() {
    asm volatile("" ::: "memory");
    __builtin_amdgcn_s_barrier();
    asm volatile("" ::: "memory");
}

// 2 waves per block, one block per batch element.
// Wave 1 (producer): global->LDS DMA via global_load_lds into a 4-region ring,
//   2 phases ahead, s_waitcnt vmcnt(16) (never 0) before each barrier.
// Wave 0 (consumer): LINEAR-domain CTC chain (per-lane power-of-2 scaling,
//   renorm every 4 steps — proven exact in R6/R7). Lane i owns states s=2i+1
//   (label) and s=2i+2 (blank); s=0 is scalar a0.
__global__ __launch_bounds__(128, 1)
void ctc_fwd_kernel(const float* __restrict__ y_pred,
                    const int*   __restrict__ labels,
                    const int*   __restrict__ input_length,
                    const int*   __restrict__ label_length,
                    float*       __restrict__ out,
                    int T, int C, int L)
{
    const int b    = blockIdx.x;
    const int wave = threadIdx.x >> 6;
    const int lane = threadIdx.x & 63;
    const int Tin  = input_length[b];
    const int ll   = label_length[b];

    __shared__ float smem[4][16][128];         // 32 KB ring: 4 phases x 16 rows
    const int NP = T / 16;                     // 32 phases

    if (wave == 1) {
        // ---------------- producer ----------------
        const float* g0 = y_pred + (size_t)b * T * C;
        auto issue_phase = [&](int ph) {
            int reg = ph & 3;
            int phc = (ph < NP) ? ph : (NP - 1);        // tail: dummy reload
            const float* g = g0 + (size_t)phc * 16 * 128;
            float* lp = &smem[reg][0][0];
            #pragma unroll
            for (int c = 0; c < 8; ++c) {               // 8 x 1KB chunks/phase
                __builtin_amdgcn_global_load_lds(
                    (const __attribute__((address_space(1))) void*)(g + c * 256 + lane * 4),
                    (__attribute__((address_space(3))) void*)(lp + c * 256),
                    16, 0, 0);                          // 16B/lane x 64 = 1KB
            }
        };
        issue_phase(0);
        issue_phase(1);
        for (int p = 0; p < NP; ++p) {
            issue_phase(p + 2);
            // outstanding: phases p(8, maybe) + p+1(8) + p+2(8); vmcnt(16)
            // waits until only the 16 newest remain -> phase p resident.
            __builtin_amdgcn_s_waitcnt(0x4F70);  // vmcnt(16), lgkm/exp no-wait
            wg_barrier();                        // phase p ready for consumer
        }
    } else {
        // ---------------- consumer ----------------
        const int  l       = labels[(size_t)b * L + lane];  // 0..C-2, never blank
        const int  lprev   = __shfl_up(l, 1);               // one-time DS op
        const bool skip    = (lane >= 1) && (l != lprev);
        const bool rowhead = ((lane & 15) == 0);
        const bool lane0   = (lane == 0);

        float a0 = 0.0f, ao = 0.0f, ae = 0.0f;
        int   esum = 0;                          // per-lane exponent tally
        float fsc  = 1.0f;                       // 2^(esum_prev - esum_self)

        for (int p = 0; p < NP; ++p) {
            wg_barrier();                        // region p&3 now holds phase p
            const int reg = p & 3;
            float ylv[16], ybv[16];
            #pragma unroll
            for (int j = 0; j < 16; ++j) {
                ylv[j] = smem[reg][j][l] + EPSF;     // divergent ds_read
                ybv[j] = smem[reg][j][127] + EPSF;   // uniform -> broadcast
            }
            #pragma unroll
            for (int j = 0; j < 16; ++j) {
                int t = p * 16 + j;
                if (t < Tin) {                       // wave-uniform
                    if (t == 0) {
                        a0 = ybv[0];
                        ao = lane0 ? ylv[0] : 0.0f;
                        ae = 0.0f;
                    } else {
                        float sae = shift_up1_f(ae, rowhead);  // alpha[2i]
                        float sao = shift_up1_f(ao, rowhead);  // alpha[2i-1]
                        float a2  = lane0 ? a0 : sae * fsc;
                        float a3  = skip ? sao * fsc : 0.0f;
                        float nao = (ao + a2 + a3) * ylv[j];   // s=2i+1
                        float nae = (ae + ao) * ybv[j];        // s=2i+2
                        a0 *= ybv[j];                          // s=0
                        ao = nao;
                        ae = nae;
                    }
                }
                if ((j & 3) == 3) {                  // renorm every 4 steps
                    float lm    = fmaxf(ae, ao);
                    float basis = (lm > 0.0f) ? lm : a0;   // a0-anchor if dead
                    int   e  = (__float_as_int(basis) >> 23) & 0xFF;
                    float sc = __int_as_float((254 - e) << 23);  // 2^(127-e)
                    ae *= sc; ao *= sc; a0 *= sc;
                    esum += e - 127;
                    int en = shift_up1_i(esum, rowhead);
                    int de = en - esum;
                    de = de < -127 ? -127 : (de > 127 ? 127 : de);
                    fsc = __int_as_float((127 + de) << 23);      // 2^de
                }
            }
        }

        // s_end = 2*ll -> lane (ll-1).ae ; s_end-1 -> lane (ll-1).ao ; ll >= 16
        if (lane == ll - 1) {
            float pfin = ae + ao;                    // lane's own scale
            out[b] = -(LOG2(pfin) + (float)esum) * LN2F;
        }
    }
}

extern "C" void kernel_launch(void* const* d_in, const int* in_sizes, int n_in,
                              void* d_out, int out_size, void* d_ws, size_t ws_size,
                              hipStream_t stream) {
    const float* y_pred       = (const float*)d_in[0];
    const int*   labels       = (const int*)d_in[1];
    const int*   input_length = (const int*)d_in[2];
    const int*   label_length = (const int*)d_in[3];
    float*       out          = (float*)d_out;

    const int B = in_sizes[2];          // 256
    const int L = in_sizes[1] / B;      // 64
    const int T = 512;
    const int C = 128;

    ctc_fwd_kernel<<<B, 128, 0, stream>>>(y_pred, labels, input_length,
                                          label_length, out, T, C, L);
}

// Round 9
// 113.514 us; speedup vs baseline: 2.7227x; 1.0122x over previous
//
#include <hip/hip_runtime.h>

#define EPSF  (1e-7f)
#define LN2F  (0.69314718055994530942f)

#if __has_builtin(__builtin_amdgcn_logf)
#define LOG2(x) __builtin_amdgcn_logf(x)
#else
#define LOG2(x) __log2f(x)
#endif

// DPP move; ctrl is a template constant. bound_ctrl=1 -> invalid lanes read 0.
template<int CTRL>
__device__ __forceinline__ int dpp_i(int x) {
    return __builtin_amdgcn_update_dpp(x, x, CTRL, 0xF, 0xF, true);
}

// Full-wave shift-up-by-1 in registers (no DS): row_shr:1 within 16-lane rows,
// row_bcast15 fills lanes 16/32/48 from 15/31/47 (bit-exact verified R2-R8).
// Lane 0 result is garbage — always selected away by callers.
__device__ __forceinline__ float shift_up1_f(float x, bool rowhead) {
    int xi = __float_as_int(x);
    int sh = dpp_i<0x111>(xi);
    int bc = dpp_i<0x142>(xi);
    return __int_as_float(rowhead ? bc : sh);
}
__device__ __forceinline__ int shift_up1_i(int x, bool rowhead) {
    int sh = dpp_i<0x111>(x);
    int bc = dpp_i<0x142>(x);
    return rowhead ? bc : sh;
}

// Raw workgroup barrier WITHOUT the compiler's vmcnt(0) drain. Residency is
// guaranteed by the producer's own fine-grained s_waitcnt before the barrier.
__device__ __forceinline__ void wg_barrier() {
    asm volatile("" ::: "memory");
    __builtin_amdgcn_s_barrier();
    asm volatile("" ::: "memory");
}

// s_waitcnt immediates (gfx9 encoding: vmcnt[3:0]@0,[5:4]@14; exp@4; lgkm@8)
#define WAITCNT_VM16_ONLY  0x4F70   // vmcnt(16), lgkm/exp no-wait
#define WAITCNT_LGKM0_ONLY 0xC07F   // lgkmcnt(0), vm/exp no-wait

// 2 waves per block, one block per batch element. T=512, C=128, L=64.
// Wave 1 (producer): (a) global->LDS DMA of 16-row phases into a 4-slot raw
//   ring, 3 phases ahead, vmcnt(16) pacing; (b) label-gather: divergent
//   ds_read of raw[j][l_i] + uniform blank raw[j][127], +EPS, packed as
//   float2 into a 2-slot compact ring (conflict-free for the consumer).
// Wave 0 (consumer): pure LINEAR-domain CTC chain (per-lane power-of-2
//   scaling, renorm every 4 steps — exact since R6). Lane i owns states
//   s=2i+1 (label) and s=2i+2 (blank); s=0 is scalar a0.
__global__ __launch_bounds__(128, 1)
void ctc_fwd_kernel(const float* __restrict__ y_pred,
                    const int*   __restrict__ labels,
                    const int*   __restrict__ input_length,
                    const int*   __restrict__ label_length,
                    float*       __restrict__ out,
                    int T, int C, int L)
{
    const int b    = blockIdx.x;
    const int wave = threadIdx.x >> 6;
    const int lane = threadIdx.x & 63;
    const int Tin  = input_length[b];
    const int ll   = label_length[b];
    const int NP   = T / 16;                   // 32 phases

    __shared__ float  raw[4][16][128];         // 32 KB raw ring
    __shared__ float2 cmp[2][16][64];          // 16 KB compact ring {yl,yb}

    const int l = labels[(size_t)b * L + lane];     // 0..C-2, never blank

    if (wave == 1) {
        // ---------------- producer ----------------
        const float* g0 = y_pred + (size_t)b * T * C;
        auto dma = [&](int ph) {
            int slot = ph & 3;
            int phc  = (ph < NP) ? ph : (NP - 1);       // tail: dummy reload
            const float* g = g0 + (size_t)phc * 16 * 128;
            float* lp = &raw[slot][0][0];
            #pragma unroll
            for (int c = 0; c < 8; ++c) {               // 8 x 1KB chunks/phase
                __builtin_amdgcn_global_load_lds(
                    (const __attribute__((address_space(1))) void*)(g + c * 256 + lane * 4),
                    (__attribute__((address_space(3))) void*)(lp + c * 256),
                    16, 0, 0);                          // 16B/lane x 64 = 1KB
            }
        };
        auto gth = [&](int ph) {                        // raw[ph] -> cmp[ph&1]
            int slot = ph & 3, par = ph & 1;
            #pragma unroll
            for (int j = 0; j < 16; ++j) {
                float v  = raw[slot][j][l];             // divergent (producer's slack)
                float bb = raw[slot][j][127];           // uniform -> broadcast
                cmp[par][j][lane] = make_float2(v + EPSF, bb + EPSF);
            }
        };
        dma(0); dma(1); dma(2);
        __builtin_amdgcn_s_waitcnt(WAITCNT_VM16_ONLY);  // raw0 resident
        gth(0);
        __builtin_amdgcn_s_waitcnt(WAITCNT_LGKM0_ONLY); // cmp0 visible
        wg_barrier();
        for (int p = 0; p < NP; ++p) {
            dma(p + 3);                                 // 24 outstanding
            __builtin_amdgcn_s_waitcnt(WAITCNT_VM16_ONLY);  // raw[p+1] resident
            gth(p + 1);                                 // (dummy at tail)
            __builtin_amdgcn_s_waitcnt(WAITCNT_LGKM0_ONLY);
            wg_barrier();                               // cmp[p+1] ready
        }
    } else {
        // ---------------- consumer ----------------
        const int  lprev   = __shfl_up(l, 1);           // one-time DS op
        const bool skip    = (lane >= 1) && (l != lprev);
        const bool rowhead = ((lane & 15) == 0);
        const bool lane0   = (lane == 0);

        float a0 = 0.0f, ao = 0.0f, ae = 0.0f;
        int   esum = 0;                          // per-lane exponent tally
        float fsc  = 1.0f;                       // 2^(esum_prev - esum_self)

        wg_barrier();                            // cmp0 ready
        for (int p = 0; p < NP; ++p) {
            const int par = p & 1;
            float ylv[16], ybv[16];
            #pragma unroll
            for (int j = 0; j < 16; ++j) {       // 16 conflict-free ds_read_b64
                float2 v = cmp[par][j][lane];
                ylv[j] = v.x; ybv[j] = v.y;
            }
            #pragma unroll
            for (int j = 0; j < 16; ++j) {
                int t = p * 16 + j;
                if (t < Tin) {                   // wave-uniform
                    if (t == 0) {
                        a0 = ybv[0];
                        ao = lane0 ? ylv[0] : 0.0f;
                        ae = 0.0f;
                    } else {
                        float sae = shift_up1_f(ae, rowhead);  // alpha[2i]
                        float sao = shift_up1_f(ao, rowhead);  // alpha[2i-1]
                        float a2  = lane0 ? a0 : sae * fsc;
                        float a3  = skip ? sao * fsc : 0.0f;
                        float nao = (ao + a2 + a3) * ylv[j];   // s=2i+1
                        float nae = (ae + ao) * ybv[j];        // s=2i+2
                        a0 *= ybv[j];                          // s=0
                        ao = nao;
                        ae = nae;
                    }
                }
                if ((j & 3) == 3) {              // renorm every 4 steps
                    float lm    = fmaxf(ae, ao);
                    float basis = (lm > 0.0f) ? lm : a0;   // a0-anchor if dead
                    int   e  = (__float_as_int(basis) >> 23) & 0xFF;
                    float sc = __int_as_float((254 - e) << 23);  // 2^(127-e)
                    ae *= sc; ao *= sc; a0 *= sc;
                    esum += e - 127;
                    int en = shift_up1_i(esum, rowhead);
                    int de = en - esum;
                    de = de < -127 ? -127 : (de > 127 ? 127 : de);
                    fsc = __int_as_float((127 + de) << 23);      // 2^de
                }
            }
            wg_barrier();                        // next phase's cmp ready
        }

        // s_end = 2*ll -> lane (ll-1).ae ; s_end-1 -> lane (ll-1).ao ; ll >= 16
        if (lane == ll - 1) {
            float pfin = ae + ao;                // lane's own scale
            out[b] = -(LOG2(pfin) + (float)esum) * LN2F;
        }
    }
}

extern "C" void kernel_launch(void* const* d_in, const int* in_sizes, int n_in,
                              void* d_out, int out_size, void* d_ws, size_t ws_size,
                              hipStream_t stream) {
    const float* y_pred       = (const float*)d_in[0];
    const int*   labels       = (const int*)d_in[1];
    const int*   input_length = (const int*)d_in[2];
    const int*   label_length = (const int*)d_in[3];
    float*       out          = (float*)d_out;

    const int B = in_sizes[2];          // 256
    const int L = in_sizes[1] / B;      // 64
    const int T = 512;
    const int C = 128;

    ctc_fwd_kernel<<<B, 128, 0, stream>>>(y_pred, labels, input_length,
                                          label_length, out, T, C, L);
}